// Round 3
// baseline (634.821 us; speedup 1.0000x reference)
//
#include <hip/hip_runtime.h>
#include <cstddef>
#include <cstdint>

typedef unsigned short u16;
typedef short s16x8 __attribute__((ext_vector_type(8)));
typedef float f32x4 __attribute__((ext_vector_type(4)));
typedef int   i32x4 __attribute__((ext_vector_type(4)));
typedef u16   u16x4 __attribute__((ext_vector_type(4)));

__device__ __forceinline__ float b2f(u16 u) {
  union { unsigned int i; float f; } v; v.i = ((unsigned int)u) << 16; return v.f;
}
__device__ __forceinline__ u16 f2b(float f) {
  union { float f; unsigned int i; } v; v.f = f;
  unsigned int r = v.i + 0x7fffu + ((v.i >> 16) & 1u);
  return (u16)(r >> 16);
}

// ---------------------------------------------------------------------------
// Transpose+cast 6 fp32 weight matrices (256x256) -> bf16 WT[n][k].
// LDS-tiled for coalescing. grid (6,16) x 256 thr; 64x64 tile per block.
// ---------------------------------------------------------------------------
__global__ __launch_bounds__(256) void transpose6(
    const float* __restrict__ w0, const float* __restrict__ w1,
    const float* __restrict__ w2, const float* __restrict__ w3,
    const float* __restrict__ w4, const float* __restrict__ w5,
    u16* __restrict__ wt)
{
  __shared__ u16 T[64][66];   // pitch 66: bank = (33j + lane/2) -> conflict-free
  const float* src;
  switch (blockIdx.x) {
    case 0: src = w0; break; case 1: src = w1; break;
    case 2: src = w2; break; case 3: src = w3; break;
    case 4: src = w4; break; default: src = w5; break;
  }
  u16* dst = wt + (size_t)blockIdx.x * 65536;
  const int tr = (blockIdx.y & 3) * 64;   // source row block
  const int tc = (blockIdx.y >> 2) * 64;  // source col block
  const int lane = threadIdx.x & 63, grp = threadIdx.x >> 6;
  #pragma unroll
  for (int i = 0; i < 16; ++i) {
    const int r = grp + i * 4;  // 0..63
    T[lane][r] = f2b(src[(size_t)(tr + r) * 256 + tc + lane]);
  }
  __syncthreads();
  #pragma unroll
  for (int i = 0; i < 16; ++i) {
    const int j = grp + i * 4;  // 0..63 (local out-row)
    dst[(size_t)(tc + j) * 256 + tr + lane] = T[j][lane];
  }
}

// ---------------------------------------------------------------------------
// FiLM precompute (fp32): emb = pos(256x256) @ W_emb(256x512) + b_emb
// shift = emb[:, :256], scale = emb[:, 256:]. grid (256,8) x 256 thr:
// block = (s, 64-col chunk), k split over 4 segments + LDS reduce.
// ---------------------------------------------------------------------------
__global__ __launch_bounds__(256) void film_kernel(
    const float* __restrict__ pos, const float* __restrict__ Wemb,
    const float* __restrict__ bemb, float* __restrict__ shift,
    float* __restrict__ scale)
{
  __shared__ float prow[256];
  __shared__ float psum[4][64];
  const int s = blockIdx.x, t = threadIdx.x;
  const int ks = t >> 6, cl = t & 63;
  const int c = blockIdx.y * 64 + cl;
  prow[t] = pos[s * 256 + t];
  __syncthreads();
  float acc = 0.f;
  #pragma unroll 8
  for (int kk = ks * 64; kk < ks * 64 + 64; ++kk)
    acc = fmaf(prow[kk], Wemb[kk * 512 + c], acc);
  psum[ks][cl] = acc;
  __syncthreads();
  if (t < 64) {
    const int cc = blockIdx.y * 64 + t;
    const float v = psum[0][t] + psum[1][t] + psum[2][t] + psum[3][t] + bemb[cc];
    if (cc < 256) shift[s * 256 + cc] = v;
    else          scale[s * 256 + cc - 256] = v;
  }
}

// ---------------------------------------------------------------------------
// LayerNorm over f=256 per token (fp32 in, bf16 out); wave per token.
// If shift != nullptr also applies FiLM: ln*(scale+1)+shift (spos = token%256).
// grid 16384 x 256 thr.
// ---------------------------------------------------------------------------
__global__ __launch_bounds__(256) void ln_kernel(
    const float* __restrict__ x, const float* __restrict__ shift,
    const float* __restrict__ scale, const float* __restrict__ g,
    const float* __restrict__ b, u16* __restrict__ out)
{
  const int token = blockIdx.x * 4 + (threadIdx.x >> 6);
  const int lane = threadIdx.x & 63;
  f32x4 v = *(const f32x4*)(x + (size_t)token * 256 + lane * 4);
  float s  = v[0] + v[1] + v[2] + v[3];
  float s2 = v[0]*v[0] + v[1]*v[1] + v[2]*v[2] + v[3]*v[3];
  #pragma unroll
  for (int off = 32; off >= 1; off >>= 1) {
    s  += __shfl_xor(s, off);
    s2 += __shfl_xor(s2, off);
  }
  const float mean = s * 0.00390625f;
  const float var  = s2 * 0.00390625f - mean * mean;
  const float inv  = rsqrtf(var + 1e-5f);
  const int spos = token & 255;
  u16x4 o;
  #pragma unroll
  for (int i = 0; i < 4; ++i) {
    const int f = lane * 4 + i;
    float ln = (v[i] - mean) * inv * g[f] + b[f];
    if (shift) ln = ln * (scale[spos * 256 + f] + 1.0f) + shift[spos * 256 + f];
    o[i] = f2b(ln);
  }
  *(u16x4*)(out + (size_t)token * 256 + lane * 4) = o;
}

// ---------------------------------------------------------------------------
// GEMM: A(65536x256) bf16 @ WT[n][k] bf16.
// 128x128 block tile, BK=64, 4 waves, wave tile 64x64 (4x4 16x16x32 MFMA).
// modes: 0 = +bias, natural bf16 store [m][n]
//        1 = +bias, transposed-per-window bf16 store vT[w][n][m%256]
//        2 = fp32 residual: out_f = extra + coef[n]*(acc+bias)
//        3 = silu(acc) bf16 store
// grid (512, 2) x 256 thr.
// ---------------------------------------------------------------------------
__global__ __launch_bounds__(256) void gemm256(
    const u16* __restrict__ A, const u16* __restrict__ BT,
    const float* __restrict__ bias, const float* extra,
    const float* __restrict__ coef, u16* __restrict__ out_b,
    float* out_f, int mode)
{
  __shared__ __align__(16) u16 Alds[128][72];  // +8 pad
  __shared__ __align__(16) u16 Blds[128][72];
  const int m0 = blockIdx.x * 128;
  const int n0 = blockIdx.y * 128;
  const int t = threadIdx.x;
  const int wave = t >> 6, lane = t & 63;
  const int wm = (wave & 1) * 64, wn = (wave >> 1) * 64;
  const int lrow = lane & 15, lk = (lane >> 4) * 8;

  f32x4 acc[4][4];
  #pragma unroll
  for (int i = 0; i < 4; ++i)
    #pragma unroll
    for (int j = 0; j < 4; ++j)
      acc[i][j] = f32x4{0.f, 0.f, 0.f, 0.f};

  for (int k0 = 0; k0 < 256; k0 += 64) {
    #pragma unroll
    for (int i = 0; i < 4; ++i) {
      const int c = i * 256 + t;
      const int row = c >> 3, col = (c & 7) * 8;
      *(i32x4*)(&Alds[row][col]) = *(const i32x4*)(A  + (size_t)(m0 + row) * 256 + k0 + col);
      *(i32x4*)(&Blds[row][col]) = *(const i32x4*)(BT + (size_t)(n0 + row) * 256 + k0 + col);
    }
    __syncthreads();
    #pragma unroll
    for (int kk = 0; kk < 64; kk += 32) {
      s16x8 af[4], bf[4];
      #pragma unroll
      for (int mt = 0; mt < 4; ++mt) af[mt] = *(const s16x8*)(&Alds[wm + mt*16 + lrow][kk + lk]);
      #pragma unroll
      for (int nt = 0; nt < 4; ++nt) bf[nt] = *(const s16x8*)(&Blds[wn + nt*16 + lrow][kk + lk]);
      #pragma unroll
      for (int mt = 0; mt < 4; ++mt)
        #pragma unroll
        for (int nt = 0; nt < 4; ++nt)
          acc[mt][nt] = __builtin_amdgcn_mfma_f32_16x16x32_bf16(af[mt], bf[nt], acc[mt][nt], 0, 0, 0);
    }
    __syncthreads();
  }

  #pragma unroll
  for (int mt = 0; mt < 4; ++mt) {
    const int mb = m0 + wm + mt*16 + (lane >> 4) * 4;
    #pragma unroll
    for (int nt = 0; nt < 4; ++nt) {
      const int n = n0 + wn + nt*16 + lrow;
      const float bv = bias ? bias[n] : 0.0f;
      if (mode == 1) {
        u16x4 pk;
        #pragma unroll
        for (int r = 0; r < 4; ++r) pk[r] = f2b(acc[mt][nt][r] + bv);
        const int w = mb >> 8, ti = mb & 255;
        *(u16x4*)(out_b + (size_t)w * 65536 + (size_t)n * 256 + ti) = pk;
      } else {
        #pragma unroll
        for (int r = 0; r < 4; ++r) {
          const int m = mb + r;
          const size_t oi = (size_t)m * 256 + n;
          const float y = acc[mt][nt][r] + bv;
          if (mode == 0)      out_b[oi] = f2b(y);
          else if (mode == 3) out_b[oi] = f2b(y / (1.0f + __expf(-y)));
          else                out_f[oi] = extra[oi] + coef[n] * y; // mode 2
        }
      }
    }
  }
}

// ---------------------------------------------------------------------------
// Attention v2: block = (window, head, 64-query tile), 4 waves.
// Wave owns a 16-query slab x all 256 keys:
//   QK: 16 MFMAs -> 64 fp32 acc regs (S slab in C-layout).
//   Softmax fully in registers (quad shfl_xor reductions; inv rowsum kept).
//   Single LDS transit: P C-layout -> A-layout (per-wave-private region,
//   scalar b16 writes conflict-free, b128 reads).
//   PV: 16 MFMAs, V from pre-transposed vt[w][dim][token].
// grid (256, 8, 4) x 256 thr.
// ---------------------------------------------------------------------------
__global__ __launch_bounds__(256) void attn256(
    const u16* __restrict__ q, const u16* __restrict__ k,
    const u16* __restrict__ vt, const int* __restrict__ mask,
    u16* __restrict__ out)
{
  __shared__ __align__(16) u16 P[4][16][264];  // per-wave P slab, pitch 264
  __shared__ float bias[256];
  const int w = blockIdx.x, h = blockIdx.y, q0 = blockIdx.z * 64;
  const int t = threadIdx.x;
  const int wave = t >> 6, lane = t & 63;
  const int col = lane & 15, quad = lane >> 4;
  const size_t base = (size_t)w * 65536;
  const float sc = 0.17677669529663687f; // 1/sqrt(32)

  bias[t] = (mask[w * 256 + t] != 0) ? 0.0f : -1e9f;
  __syncthreads();

  // ---- QK: S[quad*4+r][tl*16+col] = acc[tl][r]
  const int hq = h * 32 + quad * 8;
  const int qr0 = q0 + wave * 16;
  const s16x8 af = *(const s16x8*)(q + base + (size_t)(qr0 + col) * 256 + hq);
  f32x4 acc[16];
  #pragma unroll
  for (int tl = 0; tl < 16; ++tl) {
    const s16x8 bf = *(const s16x8*)(k + base + (size_t)(tl * 16 + col) * 256 + hq);
    acc[tl] = __builtin_amdgcn_mfma_f32_16x16x32_bf16(af, bf, f32x4{0.f,0.f,0.f,0.f}, 0, 0, 0);
  }

  // ---- softmax in registers (per r-row: max over 16 in-lane + 16 lanes)
  float mb[16];
  #pragma unroll
  for (int tl = 0; tl < 16; ++tl) mb[tl] = bias[tl * 16 + col];
  float inv[4];
  #pragma unroll
  for (int r = 0; r < 4; ++r) {
    float mx = -3.0e38f;
    #pragma unroll
    for (int tl = 0; tl < 16; ++tl) {
      const float p = fmaf(acc[tl][r], sc, mb[tl]);
      acc[tl][r] = p;
      mx = fmaxf(mx, p);
    }
    mx = fmaxf(mx, __shfl_xor(mx, 1));
    mx = fmaxf(mx, __shfl_xor(mx, 2));
    mx = fmaxf(mx, __shfl_xor(mx, 4));
    mx = fmaxf(mx, __shfl_xor(mx, 8));
    float sum = 0.f;
    #pragma unroll
    for (int tl = 0; tl < 16; ++tl) {
      const float e = __expf(acc[tl][r] - mx);
      acc[tl][r] = e;
      sum += e;
    }
    sum += __shfl_xor(sum, 1);
    sum += __shfl_xor(sum, 2);
    sum += __shfl_xor(sum, 4);
    sum += __shfl_xor(sum, 8);
    inv[r] = 1.0f / sum;
  }

  // ---- P -> LDS (C-layout scatter; 2-way max bank alias = free)
  #pragma unroll
  for (int tl = 0; tl < 16; ++tl)
    #pragma unroll
    for (int r = 0; r < 4; ++r)
      P[wave][quad * 4 + r][tl * 16 + col] = f2b(acc[tl][r]);
  __syncthreads();

  // ---- PV: O(16x32) += P(16x256) @ V(256x32)
  f32x4 o0 = {0.f,0.f,0.f,0.f}, o1 = {0.f,0.f,0.f,0.f};
  const u16* vb = vt + base + (size_t)(h * 32) * 256;
  #pragma unroll
  for (int s = 0; s < 8; ++s) {
    const s16x8 pf  = *(const s16x8*)(&P[wave][col][s * 32 + quad * 8]);
    const s16x8 vf0 = *(const s16x8*)(vb + (size_t)col * 256 + s * 32 + quad * 8);
    const s16x8 vf1 = *(const s16x8*)(vb + (size_t)(16 + col) * 256 + s * 32 + quad * 8);
    o0 = __builtin_amdgcn_mfma_f32_16x16x32_bf16(pf, vf0, o0, 0, 0, 0);
    o1 = __builtin_amdgcn_mfma_f32_16x16x32_bf16(pf, vf1, o1, 0, 0, 0);
  }

  // ---- epilogue: normalize by rowsum, store
  #pragma unroll
  for (int r = 0; r < 4; ++r) {
    const size_t oa = base + (size_t)(qr0 + quad * 4 + r) * 256 + h * 32;
    out[oa + col]      = f2b(o0[r] * inv[r]);
    out[oa + 16 + col] = f2b(o1[r] * inv[r]);
  }
}

// ---------------------------------------------------------------------------
// mask_update = mask & all(mask over window); write fp32 1.0/0.0. grid 256.
// ---------------------------------------------------------------------------
__global__ __launch_bounds__(256) void maskup(const int* __restrict__ mask,
                                              float* __restrict__ out)
{
  __shared__ int wall[4];
  const int w = blockIdx.x, t = threadIdx.x;
  const int v = (mask[w * 256 + t] != 0) ? 1 : 0;
  const int a = __all(v);
  if ((t & 63) == 0) wall[t >> 6] = a;
  __syncthreads();
  const int allw = wall[0] & wall[1] & wall[2] & wall[3];
  out[w * 256 + t] = (v & allw) ? 1.0f : 0.0f;
}

// ---------------------------------------------------------------------------
extern "C" void kernel_launch(void* const* d_in, const int* in_sizes, int n_in,
                              void* d_out, int out_size, void* d_ws, size_t ws_size,
                              hipStream_t stream)
{
  (void)in_sizes; (void)n_in; (void)out_size; (void)ws_size;
  const float* x    = (const float*)d_in[0];
  const int*   mask = (const int*)d_in[1];
  const float* pos  = (const float*)d_in[2];
  const float* Wemb = (const float*)d_in[3];
  const float* bemb = (const float*)d_in[4];
  const float* ln1g = (const float*)d_in[5];
  const float* ln1b = (const float*)d_in[6];
  const float* Wq   = (const float*)d_in[7];
  const float* bq   = (const float*)d_in[8];
  const float* Wk   = (const float*)d_in[9];
  const float* bk   = (const float*)d_in[10];
  const float* Wv   = (const float*)d_in[11];
  const float* bv   = (const float*)d_in[12];
  const float* Wo   = (const float*)d_in[13];
  const float* bo   = (const float*)d_in[14];
  const float* ln2g = (const float*)d_in[15];
  const float* ln2b = (const float*)d_in[16];
  const float* W1   = (const float*)d_in[17];
  const float* W2   = (const float*)d_in[18];
  const float* gam  = (const float*)d_in[19];
  const float* gml  = (const float*)d_in[20];

  char* ws = (char*)d_ws;
  float* shift = (float*)ws;                       // 256 KB
  float* scale = (float*)(ws + (256 << 10));       // 256 KB
  u16*   wt    = (u16*)(ws + (512 << 10));         // 768 KB (6 x 256x256)
  u16*   b0    = (u16*)(ws + ((size_t)2  << 20));  // xm  -> attn_out
  u16*   b1    = (u16*)(ws + ((size_t)34 << 20));  // q   -> ln2_out
  u16*   b2    = (u16*)(ws + ((size_t)66 << 20));  // k   -> h(silu)
  u16*   b3    = (u16*)(ws + ((size_t)98 << 20));  // vT
  float* outx  = (float*)d_out;                    // also fp32 x1 scratch
  float* outm  = outx + 16777216;

  const u16* WqT = wt;
  const u16* WkT = wt + 65536;
  const u16* WvT = wt + 2 * 65536;
  const u16* WoT = wt + 3 * 65536;
  const u16* W1T = wt + 4 * 65536;
  const u16* W2T = wt + 5 * 65536;

  transpose6<<<dim3(6, 16), 256, 0, stream>>>(Wq, Wk, Wv, Wo, W1, W2, wt);
  film_kernel<<<dim3(256, 8), 256, 0, stream>>>(pos, Wemb, bemb, shift, scale);
  ln_kernel<<<16384, 256, 0, stream>>>(x, shift, scale, ln1g, ln1b, b0);
  gemm256<<<dim3(512, 2), 256, 0, stream>>>(b0, WqT, bq, nullptr, nullptr, b1, nullptr, 0);
  gemm256<<<dim3(512, 2), 256, 0, stream>>>(b0, WkT, bk, nullptr, nullptr, b2, nullptr, 0);
  gemm256<<<dim3(512, 2), 256, 0, stream>>>(b0, WvT, bv, nullptr, nullptr, b3, nullptr, 1);
  attn256<<<dim3(256, 8, 4), 256, 0, stream>>>(b1, b2, b3, mask, b0);
  // x1 = x + gamma * (attn_out @ Wo + bo)  -> fp32, stored in d_out x-region
  gemm256<<<dim3(512, 2), 256, 0, stream>>>(b0, WoT, bo, x, gam, nullptr, outx, 2);
  ln_kernel<<<16384, 256, 0, stream>>>(outx, nullptr, nullptr, ln2g, ln2b, b1);
  gemm256<<<dim3(512, 2), 256, 0, stream>>>(b1, W1T, nullptr, nullptr, nullptr, b2, nullptr, 3);
  // x_out = x1 + gamma_mlp * (h @ W2)  -> in-place on d_out
  gemm256<<<dim3(512, 2), 256, 0, stream>>>(b2, W2T, nullptr, outx, gml, nullptr, outx, 2);
  maskup<<<256, 256, 0, stream>>>(mask, outm);
}

// Round 4
// 526.038 us; speedup vs baseline: 1.2068x; 1.2068x over previous
//
#include <hip/hip_runtime.h>
#include <cstddef>
#include <cstdint>

typedef unsigned short u16;
typedef short s16x8 __attribute__((ext_vector_type(8)));
typedef float f32x4 __attribute__((ext_vector_type(4)));
typedef int   i32x4 __attribute__((ext_vector_type(4)));
typedef u16   u16x4 __attribute__((ext_vector_type(4)));

#if defined(__has_builtin)
#if __has_builtin(__builtin_amdgcn_exp2f)
#define EXP2F(x) __builtin_amdgcn_exp2f(x)
#else
#define EXP2F(x) exp2f(x)
#endif
#else
#define EXP2F(x) exp2f(x)
#endif

__device__ __forceinline__ float b2f(u16 u) {
  union { unsigned int i; float f; } v; v.i = ((unsigned int)u) << 16; return v.f;
}
__device__ __forceinline__ u16 f2b(float f) {
  union { float f; unsigned int i; } v; v.f = f;
  unsigned int r = v.i + 0x7fffu + ((v.i >> 16) & 1u);
  return (u16)(r >> 16);
}

// ---------------------------------------------------------------------------
// Transpose+cast 6 fp32 weight matrices (256x256) -> bf16 WT[n][k].
// grid (6,16) x 256 thr; 64x64 tile per block.
// ---------------------------------------------------------------------------
__global__ __launch_bounds__(256) void transpose6(
    const float* __restrict__ w0, const float* __restrict__ w1,
    const float* __restrict__ w2, const float* __restrict__ w3,
    const float* __restrict__ w4, const float* __restrict__ w5,
    u16* __restrict__ wt)
{
  __shared__ u16 T[64][66];
  const float* src;
  switch (blockIdx.x) {
    case 0: src = w0; break; case 1: src = w1; break;
    case 2: src = w2; break; case 3: src = w3; break;
    case 4: src = w4; break; default: src = w5; break;
  }
  u16* dst = wt + (size_t)blockIdx.x * 65536;
  const int tr = (blockIdx.y & 3) * 64;
  const int tc = (blockIdx.y >> 2) * 64;
  const int lane = threadIdx.x & 63, grp = threadIdx.x >> 6;
  #pragma unroll
  for (int i = 0; i < 16; ++i) {
    const int r = grp + i * 4;
    T[lane][r] = f2b(src[(size_t)(tr + r) * 256 + tc + lane]);
  }
  __syncthreads();
  #pragma unroll
  for (int i = 0; i < 16; ++i) {
    const int j = grp + i * 4;
    dst[(size_t)(tc + j) * 256 + tr + lane] = T[j][lane];
  }
}

// ---------------------------------------------------------------------------
// FiLM precompute (fp32): emb = pos(256x256) @ W_emb(256x512) + b_emb
// grid (256,8) x 256 thr.
// ---------------------------------------------------------------------------
__global__ __launch_bounds__(256) void film_kernel(
    const float* __restrict__ pos, const float* __restrict__ Wemb,
    const float* __restrict__ bemb, float* __restrict__ shift,
    float* __restrict__ scale)
{
  __shared__ float prow[256];
  __shared__ float psum[4][64];
  const int s = blockIdx.x, t = threadIdx.x;
  const int ks = t >> 6, cl = t & 63;
  const int c = blockIdx.y * 64 + cl;
  prow[t] = pos[s * 256 + t];
  __syncthreads();
  float acc = 0.f;
  #pragma unroll 8
  for (int kk = ks * 64; kk < ks * 64 + 64; ++kk)
    acc = fmaf(prow[kk], Wemb[kk * 512 + c], acc);
  psum[ks][cl] = acc;
  __syncthreads();
  if (t < 64) {
    const int cc = blockIdx.y * 64 + t;
    const float v = psum[0][t] + psum[1][t] + psum[2][t] + psum[3][t] + bemb[cc];
    if (cc < 256) shift[s * 256 + cc] = v;
    else          scale[s * 256 + cc - 256] = v;
  }
}

// ---------------------------------------------------------------------------
// LayerNorm over f=256 per token; wave per token. fp32 (xf) or bf16 (xb) in.
// If shift != nullptr applies FiLM. grid 16384 x 256 thr.
// ---------------------------------------------------------------------------
__global__ __launch_bounds__(256) void ln_kernel(
    const float* __restrict__ xf, const u16* __restrict__ xb,
    const float* __restrict__ shift, const float* __restrict__ scale,
    const float* __restrict__ g, const float* __restrict__ b,
    u16* __restrict__ out)
{
  const int token = blockIdx.x * 4 + (threadIdx.x >> 6);
  const int lane = threadIdx.x & 63;
  float v[4];
  if (xf) {
    f32x4 vv = *(const f32x4*)(xf + (size_t)token * 256 + lane * 4);
    #pragma unroll
    for (int i = 0; i < 4; ++i) v[i] = vv[i];
  } else {
    u16x4 raw = *(const u16x4*)(xb + (size_t)token * 256 + lane * 4);
    #pragma unroll
    for (int i = 0; i < 4; ++i) v[i] = b2f(raw[i]);
  }
  float s  = v[0] + v[1] + v[2] + v[3];
  float s2 = v[0]*v[0] + v[1]*v[1] + v[2]*v[2] + v[3]*v[3];
  #pragma unroll
  for (int off = 32; off >= 1; off >>= 1) {
    s  += __shfl_xor(s, off);
    s2 += __shfl_xor(s2, off);
  }
  const float mean = s * 0.00390625f;
  const float var  = s2 * 0.00390625f - mean * mean;
  const float inv  = rsqrtf(var + 1e-5f);
  const int spos = token & 255;
  u16x4 o;
  #pragma unroll
  for (int i = 0; i < 4; ++i) {
    const int f = lane * 4 + i;
    float ln = (v[i] - mean) * inv * g[f] + b[f];
    if (shift) ln = ln * (scale[spos * 256 + f] + 1.0f) + shift[spos * 256 + f];
    o[i] = f2b(ln);
  }
  *(u16x4*)(out + (size_t)token * 256 + lane * 4) = o;
}

// ---------------------------------------------------------------------------
// Fused QKV GEMM: A(65536x256) bf16 @ {WqT,WkT,WvT}.
// grid (512, 6): y>>1 selects weight, y&1 selects n-half.
// q,k stored head-major [w][h][t][32]; v stored PV-frag-swizzled
// [w][h][s][qp][d][j] (token = s*32+qp*8+j, d = head dim).
// ---------------------------------------------------------------------------
__global__ __launch_bounds__(256) void gemm_qkv(
    const u16* __restrict__ A, const u16* __restrict__ wt,
    const float* __restrict__ bq, const float* __restrict__ bk,
    const float* __restrict__ bv, u16* __restrict__ qo,
    u16* __restrict__ ko, u16* __restrict__ vo)
{
  __shared__ __align__(16) u16 Alds[128][72];
  __shared__ __align__(16) u16 Blds[128][72];
  const int wsel = blockIdx.y >> 1;
  const int m0 = blockIdx.x * 128;
  const int n0 = (blockIdx.y & 1) * 128;
  const u16* BT = wt + (size_t)wsel * 65536;
  const int t = threadIdx.x;
  const int wave = t >> 6, lane = t & 63;
  const int wm = (wave & 1) * 64, wn = (wave >> 1) * 64;
  const int lrow = lane & 15, lk = (lane >> 4) * 8;

  f32x4 acc[4][4];
  #pragma unroll
  for (int i = 0; i < 4; ++i)
    #pragma unroll
    for (int j = 0; j < 4; ++j)
      acc[i][j] = f32x4{0.f, 0.f, 0.f, 0.f};

  for (int k0 = 0; k0 < 256; k0 += 64) {
    #pragma unroll
    for (int i = 0; i < 4; ++i) {
      const int c = i * 256 + t;
      const int row = c >> 3, col = (c & 7) * 8;
      *(i32x4*)(&Alds[row][col]) = *(const i32x4*)(A  + (size_t)(m0 + row) * 256 + k0 + col);
      *(i32x4*)(&Blds[row][col]) = *(const i32x4*)(BT + (size_t)(n0 + row) * 256 + k0 + col);
    }
    __syncthreads();
    #pragma unroll
    for (int kk = 0; kk < 64; kk += 32) {
      s16x8 af[4], bf[4];
      #pragma unroll
      for (int mt = 0; mt < 4; ++mt) af[mt] = *(const s16x8*)(&Alds[wm + mt*16 + lrow][kk + lk]);
      #pragma unroll
      for (int nt = 0; nt < 4; ++nt) bf[nt] = *(const s16x8*)(&Blds[wn + nt*16 + lrow][kk + lk]);
      #pragma unroll
      for (int mt = 0; mt < 4; ++mt)
        #pragma unroll
        for (int nt = 0; nt < 4; ++nt)
          acc[mt][nt] = __builtin_amdgcn_mfma_f32_16x16x32_bf16(af[mt], bf[nt], acc[mt][nt], 0, 0, 0);
    }
    __syncthreads();
  }

  const float* bias = (wsel == 0) ? bq : (wsel == 1) ? bk : bv;
  u16* qko = (wsel == 0) ? qo : ko;
  #pragma unroll
  for (int mt = 0; mt < 4; ++mt) {
    const int mb = m0 + wm + mt*16 + (lane >> 4) * 4;
    const int w = mb >> 8, tok = mb & 255;
    #pragma unroll
    for (int nt = 0; nt < 4; ++nt) {
      const int n = n0 + wn + nt*16 + lrow;
      const int h = n >> 5, d = n & 31;
      const float bv_ = bias[n];
      if (wsel < 2) {
        #pragma unroll
        for (int r = 0; r < 4; ++r)
          qko[(size_t)w * 65536 + h * 8192 + (tok + r) * 32 + d] = f2b(acc[mt][nt][r] + bv_);
      } else {
        u16x4 pk;
        #pragma unroll
        for (int r = 0; r < 4; ++r) pk[r] = f2b(acc[mt][nt][r] + bv_);
        const int sgrp = tok >> 5, qp = (tok >> 3) & 3, j0 = tok & 7;
        *(u16x4*)(vo + (size_t)w * 65536 + h * 8192 + sgrp * 1024 + qp * 256 + d * 8 + j0) = pk;
      }
    }
  }
}

// ---------------------------------------------------------------------------
// GEMM: A(65536x256) bf16 @ WT[n][k] bf16. 128x128 tile, BK=64, 4 waves.
// modes: 2 = bf16 out = extra_f + coef[n]*(acc+bias)        (Wo -> x1 bf16)
//        3 = bf16 out = silu(acc)                            (W1)
//        6 = fp32 out = b2f(extra_b) + coef[n]*acc           (W2 -> final x)
// grid (512, 2) x 256 thr.
// ---------------------------------------------------------------------------
__global__ __launch_bounds__(256) void gemm256(
    const u16* __restrict__ A, const u16* __restrict__ BT,
    const float* __restrict__ bias, const float* __restrict__ extra_f,
    const u16* __restrict__ extra_b, const float* __restrict__ coef,
    u16* __restrict__ out_b, float* __restrict__ out_f, int mode)
{
  __shared__ __align__(16) u16 Alds[128][72];
  __shared__ __align__(16) u16 Blds[128][72];
  const int m0 = blockIdx.x * 128;
  const int n0 = blockIdx.y * 128;
  const int t = threadIdx.x;
  const int wave = t >> 6, lane = t & 63;
  const int wm = (wave & 1) * 64, wn = (wave >> 1) * 64;
  const int lrow = lane & 15, lk = (lane >> 4) * 8;

  f32x4 acc[4][4];
  #pragma unroll
  for (int i = 0; i < 4; ++i)
    #pragma unroll
    for (int j = 0; j < 4; ++j)
      acc[i][j] = f32x4{0.f, 0.f, 0.f, 0.f};

  for (int k0 = 0; k0 < 256; k0 += 64) {
    #pragma unroll
    for (int i = 0; i < 4; ++i) {
      const int c = i * 256 + t;
      const int row = c >> 3, col = (c & 7) * 8;
      *(i32x4*)(&Alds[row][col]) = *(const i32x4*)(A  + (size_t)(m0 + row) * 256 + k0 + col);
      *(i32x4*)(&Blds[row][col]) = *(const i32x4*)(BT + (size_t)(n0 + row) * 256 + k0 + col);
    }
    __syncthreads();
    #pragma unroll
    for (int kk = 0; kk < 64; kk += 32) {
      s16x8 af[4], bf[4];
      #pragma unroll
      for (int mt = 0; mt < 4; ++mt) af[mt] = *(const s16x8*)(&Alds[wm + mt*16 + lrow][kk + lk]);
      #pragma unroll
      for (int nt = 0; nt < 4; ++nt) bf[nt] = *(const s16x8*)(&Blds[wn + nt*16 + lrow][kk + lk]);
      #pragma unroll
      for (int mt = 0; mt < 4; ++mt)
        #pragma unroll
        for (int nt = 0; nt < 4; ++nt)
          acc[mt][nt] = __builtin_amdgcn_mfma_f32_16x16x32_bf16(af[mt], bf[nt], acc[mt][nt], 0, 0, 0);
    }
    __syncthreads();
  }

  #pragma unroll
  for (int mt = 0; mt < 4; ++mt) {
    const int mb = m0 + wm + mt*16 + (lane >> 4) * 4;
    #pragma unroll
    for (int nt = 0; nt < 4; ++nt) {
      const int n = n0 + wn + nt*16 + lrow;
      const float bv = bias ? bias[n] : 0.0f;
      #pragma unroll
      for (int r = 0; r < 4; ++r) {
        const int m = mb + r;
        const size_t oi = (size_t)m * 256 + n;
        const float y = acc[mt][nt][r] + bv;
        if (mode == 2)      out_b[oi] = f2b(extra_f[oi] + coef[n] * y);
        else if (mode == 3) out_b[oi] = f2b(y / (1.0f + __expf(-y)));
        else                out_f[oi] = b2f(extra_b[oi]) + coef[n] * y; // mode 6
      }
    }
  }
}

// ---------------------------------------------------------------------------
// Attention v3: block = (window, head, 64-query tile), 4 waves, NO barriers.
// Wave = 16 queries x 256 keys. Head-major q/k + swizzled v -> all global
// loads 16B/lane coalesced. Register softmax in exp2 domain. Single
// wave-private LDS transit for P (C->A layout) + O bounce for vector stores.
// grid (256, 8, 4) x 256 thr.
// ---------------------------------------------------------------------------
__global__ __launch_bounds__(256) void attn256(
    const u16* __restrict__ q, const u16* __restrict__ k,
    const u16* __restrict__ vt, const int* __restrict__ mask,
    u16* __restrict__ out)
{
  __shared__ __align__(16) u16 P[4][16][264];
  const int w = blockIdx.x, h = blockIdx.y, q0 = blockIdx.z * 64;
  const int t = threadIdx.x;
  const int wave = t >> 6, lane = t & 63;
  const int col = lane & 15, quad = lane >> 4;
  const size_t hb = (size_t)w * 65536 + (size_t)h * 8192;
  const int qr0 = q0 + wave * 16;
  const float sc2 = 0.25508586f;  // (1/sqrt(32)) * log2(e)

  // mask bias per owned key column (log2 domain)
  float mbias[16];
  #pragma unroll
  for (int tl = 0; tl < 16; ++tl)
    mbias[tl] = (mask[w * 256 + tl * 16 + col] != 0) ? 0.0f : -1.0e9f;

  // ---- QK
  const s16x8 af = *(const s16x8*)(q + hb + (qr0 + col) * 32 + quad * 8);
  f32x4 acc[16];
  s16x8 kf[8];
  #pragma unroll
  for (int j = 0; j < 8; ++j)
    kf[j] = *(const s16x8*)(k + hb + (j * 16 + col) * 32 + quad * 8);
  #pragma unroll
  for (int j = 0; j < 8; ++j) {
    acc[j] = __builtin_amdgcn_mfma_f32_16x16x32_bf16(af, kf[j], f32x4{0.f,0.f,0.f,0.f}, 0, 0, 0);
    kf[j] = *(const s16x8*)(k + hb + ((8 + j) * 16 + col) * 32 + quad * 8);
  }
  #pragma unroll
  for (int j = 0; j < 8; ++j)
    acc[8 + j] = __builtin_amdgcn_mfma_f32_16x16x32_bf16(af, kf[j], f32x4{0.f,0.f,0.f,0.f}, 0, 0, 0);

  // ---- register softmax (exp2 domain), rows owned by 16-lane groups
  float inv[4];
  #pragma unroll
  for (int r = 0; r < 4; ++r) {
    float mx = -3.0e38f;
    #pragma unroll
    for (int tl = 0; tl < 16; ++tl) {
      const float p = fmaf(acc[tl][r], sc2, mbias[tl]);
      acc[tl][r] = p;
      mx = fmaxf(mx, p);
    }
    mx = fmaxf(mx, __shfl_xor(mx, 1));
    mx = fmaxf(mx, __shfl_xor(mx, 2));
    mx = fmaxf(mx, __shfl_xor(mx, 4));
    mx = fmaxf(mx, __shfl_xor(mx, 8));
    float sum = 0.f;
    #pragma unroll
    for (int tl = 0; tl < 16; ++tl) {
      const float e = EXP2F(acc[tl][r] - mx);
      acc[tl][r] = e;
      sum += e;
    }
    sum += __shfl_xor(sum, 1);
    sum += __shfl_xor(sum, 2);
    sum += __shfl_xor(sum, 4);
    sum += __shfl_xor(sum, 8);
    inv[r] = 1.0f / sum;
  }

  // ---- P -> wave-private LDS (C-layout scatter)
  #pragma unroll
  for (int tl = 0; tl < 16; ++tl)
    #pragma unroll
    for (int r = 0; r < 4; ++r)
      P[wave][quad * 4 + r][tl * 16 + col] = f2b(acc[tl][r]);

  // ---- PV: O(16x32) = P(16x256) @ V(256x32), V pre-swizzled -> coalesced
  f32x4 o0 = {0.f,0.f,0.f,0.f}, o1 = {0.f,0.f,0.f,0.f};
  const u16* vb = vt + hb;
  #pragma unroll
  for (int s = 0; s < 8; ++s) {
    const s16x8 pf  = *(const s16x8*)(&P[wave][col][s * 32 + quad * 8]);
    const s16x8 vf0 = *(const s16x8*)(vb + s * 1024 + quad * 256 + col * 8);
    const s16x8 vf1 = *(const s16x8*)(vb + s * 1024 + quad * 256 + col * 8 + 128);
    o0 = __builtin_amdgcn_mfma_f32_16x16x32_bf16(pf, vf0, o0, 0, 0, 0);
    o1 = __builtin_amdgcn_mfma_f32_16x16x32_bf16(pf, vf1, o1, 0, 0, 0);
  }

  // ---- bounce O through the (now free) P slab for 16B/lane stores
  #pragma unroll
  for (int r = 0; r < 4; ++r) {
    P[wave][quad * 4 + r][col]      = f2b(o0[r] * inv[r]);
    P[wave][quad * 4 + r][col + 16] = f2b(o1[r] * inv[r]);
  }
  const s16x8 ov = *(const s16x8*)(&P[wave][col][quad * 8]);
  *(s16x8*)(out + (size_t)w * 65536 + (size_t)(qr0 + col) * 256 + h * 32 + quad * 8) = ov;
}

// ---------------------------------------------------------------------------
// mask_update. grid 256 x 256.
// ---------------------------------------------------------------------------
__global__ __launch_bounds__(256) void maskup(const int* __restrict__ mask,
                                              float* __restrict__ out)
{
  __shared__ int wall[4];
  const int w = blockIdx.x, t = threadIdx.x;
  const int v = (mask[w * 256 + t] != 0) ? 1 : 0;
  const int a = __all(v);
  if ((t & 63) == 0) wall[t >> 6] = a;
  __syncthreads();
  const int allw = wall[0] & wall[1] & wall[2] & wall[3];
  out[w * 256 + t] = (v & allw) ? 1.0f : 0.0f;
}

// ---------------------------------------------------------------------------
extern "C" void kernel_launch(void* const* d_in, const int* in_sizes, int n_in,
                              void* d_out, int out_size, void* d_ws, size_t ws_size,
                              hipStream_t stream)
{
  (void)in_sizes; (void)n_in; (void)out_size; (void)ws_size;
  const float* x    = (const float*)d_in[0];
  const int*   mask = (const int*)d_in[1];
  const float* pos  = (const float*)d_in[2];
  const float* Wemb = (const float*)d_in[3];
  const float* bemb = (const float*)d_in[4];
  const float* ln1g = (const float*)d_in[5];
  const float* ln1b = (const float*)d_in[6];
  const float* Wq   = (const float*)d_in[7];
  const float* bq   = (const float*)d_in[8];
  const float* Wk   = (const float*)d_in[9];
  const float* bk   = (const float*)d_in[10];
  const float* Wv   = (const float*)d_in[11];
  const float* bv   = (const float*)d_in[12];
  const float* Wo   = (const float*)d_in[13];
  const float* bo   = (const float*)d_in[14];
  const float* ln2g = (const float*)d_in[15];
  const float* ln2b = (const float*)d_in[16];
  const float* W1   = (const float*)d_in[17];
  const float* W2   = (const float*)d_in[18];
  const float* gam  = (const float*)d_in[19];
  const float* gml  = (const float*)d_in[20];

  char* ws = (char*)d_ws;
  float* shift = (float*)ws;                       // 256 KB
  float* scale = (float*)(ws + (256 << 10));       // 256 KB
  u16*   wt    = (u16*)(ws + (512 << 10));         // 768 KB (6 x 256x256)
  u16*   b0    = (u16*)(ws + ((size_t)2  << 20));  // xm   -> attn_out
  u16*   b1    = (u16*)(ws + ((size_t)34 << 20));  // q^   -> x1 (bf16)
  u16*   b2    = (u16*)(ws + ((size_t)66 << 20));  // k^   -> ln2_out
  u16*   b3    = (u16*)(ws + ((size_t)98 << 20));  // V~   -> silu(h1)
  float* outx  = (float*)d_out;
  float* outm  = outx + 16777216;

  const u16* WoT = wt + 3 * 65536;
  const u16* W1T = wt + 4 * 65536;
  const u16* W2T = wt + 5 * 65536;

  transpose6<<<dim3(6, 16), 256, 0, stream>>>(Wq, Wk, Wv, Wo, W1, W2, wt);
  film_kernel<<<dim3(256, 8), 256, 0, stream>>>(pos, Wemb, bemb, shift, scale);
  ln_kernel<<<16384, 256, 0, stream>>>(x, nullptr, shift, scale, ln1g, ln1b, b0);
  gemm_qkv<<<dim3(512, 6), 256, 0, stream>>>(b0, wt, bq, bk, bv, b1, b2, b3);
  attn256<<<dim3(256, 8, 4), 256, 0, stream>>>(b1, b2, b3, mask, b0);
  // x1 = bf16(x + gamma * (attn_out @ Wo + bo))
  gemm256<<<dim3(512, 2), 256, 0, stream>>>(b0, WoT, bo, x, nullptr, gam, b1, nullptr, 2);
  ln_kernel<<<16384, 256, 0, stream>>>(nullptr, b1, nullptr, nullptr, ln2g, ln2b, b2);
  gemm256<<<dim3(512, 2), 256, 0, stream>>>(b2, W1T, nullptr, nullptr, nullptr, nullptr, b3, nullptr, 3);
  // out = x1 + gamma_mlp * (h @ W2)   (fp32 final)
  gemm256<<<dim3(512, 2), 256, 0, stream>>>(b3, W2T, nullptr, nullptr, b1, gml, nullptr, outx, 6);
  maskup<<<256, 256, 0, stream>>>(mask, outm);
}

// Round 5
// 453.247 us; speedup vs baseline: 1.4006x; 1.1606x over previous
//
#include <hip/hip_runtime.h>
#include <cstddef>
#include <cstdint>

typedef unsigned short u16;
typedef short s16x8 __attribute__((ext_vector_type(8)));
typedef float f32x4 __attribute__((ext_vector_type(4)));
typedef int   i32x4 __attribute__((ext_vector_type(4)));
typedef u16   u16x4 __attribute__((ext_vector_type(4)));

__device__ __forceinline__ float b2f(u16 u) {
  union { unsigned int i; float f; } v; v.i = ((unsigned int)u) << 16; return v.f;
}
__device__ __forceinline__ u16 f2b(float f) {
  union { float f; unsigned int i; } v; v.f = f;
  unsigned int r = v.i + 0x7fffu + ((v.i >> 16) & 1u);
  return (u16)(r >> 16);
}

// ---------------------------------------------------------------------------
// Transpose+cast 6 fp32 weight matrices (256x256) -> bf16 WT[n][k].
// grid (6,16) x 256 thr; 64x64 tile per block.
// ---------------------------------------------------------------------------
__global__ __launch_bounds__(256) void transpose6(
    const float* __restrict__ w0, const float* __restrict__ w1,
    const float* __restrict__ w2, const float* __restrict__ w3,
    const float* __restrict__ w4, const float* __restrict__ w5,
    u16* __restrict__ wt)
{
  __shared__ u16 T[64][66];
  const float* src;
  switch (blockIdx.x) {
    case 0: src = w0; break; case 1: src = w1; break;
    case 2: src = w2; break; case 3: src = w3; break;
    case 4: src = w4; break; default: src = w5; break;
  }
  u16* dst = wt + (size_t)blockIdx.x * 65536;
  const int tr = (blockIdx.y & 3) * 64;
  const int tc = (blockIdx.y >> 2) * 64;
  const int lane = threadIdx.x & 63, grp = threadIdx.x >> 6;
  #pragma unroll
  for (int i = 0; i < 16; ++i) {
    const int r = grp + i * 4;
    T[lane][r] = f2b(src[(size_t)(tr + r) * 256 + tc + lane]);
  }
  __syncthreads();
  #pragma unroll
  for (int i = 0; i < 16; ++i) {
    const int j = grp + i * 4;
    dst[(size_t)(tc + j) * 256 + tr + lane] = T[j][lane];
  }
}

// ---------------------------------------------------------------------------
// FiLM precompute (fp32): emb = pos(256x256) @ W_emb(256x512) + b_emb
// grid (256,8) x 256 thr.
// ---------------------------------------------------------------------------
__global__ __launch_bounds__(256) void film_kernel(
    const float* __restrict__ pos, const float* __restrict__ Wemb,
    const float* __restrict__ bemb, float* __restrict__ shift,
    float* __restrict__ scale)
{
  __shared__ float prow[256];
  __shared__ float psum[4][64];
  const int s = blockIdx.x, t = threadIdx.x;
  const int ks = t >> 6, cl = t & 63;
  const int c = blockIdx.y * 64 + cl;
  prow[t] = pos[s * 256 + t];
  __syncthreads();
  float acc = 0.f;
  #pragma unroll 8
  for (int kk = ks * 64; kk < ks * 64 + 64; ++kk)
    acc = fmaf(prow[kk], Wemb[kk * 512 + c], acc);
  psum[ks][cl] = acc;
  __syncthreads();
  if (t < 64) {
    const int cc = blockIdx.y * 64 + t;
    const float v = psum[0][t] + psum[1][t] + psum[2][t] + psum[3][t] + bemb[cc];
    if (cc < 256) shift[s * 256 + cc] = v;
    else          scale[s * 256 + cc - 256] = v;
  }
}

// ---------------------------------------------------------------------------
// LayerNorm v2: token owned by a 16-lane group (4 tokens/wave, 16/block-pass).
// High MLP: 4-12 independent 16B loads per lane; 4-level intra-row shfl_xor.
// fp32 (xf) or bf16 (xb) input; optional FiLM. grid 4096 x 256 thr.
// ---------------------------------------------------------------------------
__global__ __launch_bounds__(256) void ln_kernel(
    const float* __restrict__ xf, const u16* __restrict__ xb,
    const float* __restrict__ shift, const float* __restrict__ scale,
    const float* __restrict__ g, const float* __restrict__ b,
    u16* __restrict__ out)
{
  const int lane = threadIdx.x & 63;
  const int l = lane & 15, grp = lane >> 4;
  const int token = blockIdx.x * 16 + (threadIdx.x >> 6) * 4 + grp;
  const size_t tb = (size_t)token * 256;
  const int spos = token & 255;

  if (xf) {
    // lane owns elems 4l + 64j + i  (j=0..3, i=0..3)
    f32x4 v[4];
    #pragma unroll
    for (int j = 0; j < 4; ++j) v[j] = *(const f32x4*)(xf + tb + 4 * l + 64 * j);
    float s = 0.f, s2 = 0.f;
    #pragma unroll
    for (int j = 0; j < 4; ++j)
      #pragma unroll
      for (int i = 0; i < 4; ++i) { s += v[j][i]; s2 += v[j][i] * v[j][i]; }
    #pragma unroll
    for (int off = 8; off >= 1; off >>= 1) {
      s  += __shfl_xor(s, off);
      s2 += __shfl_xor(s2, off);
    }
    const float mean = s * 0.00390625f;
    const float inv  = rsqrtf(s2 * 0.00390625f - mean * mean + 1e-5f);
    #pragma unroll
    for (int j = 0; j < 4; ++j) {
      const int e = 4 * l + 64 * j;
      const f32x4 gv = *(const f32x4*)(g + e);
      const f32x4 bv = *(const f32x4*)(b + e);
      f32x4 sc = {0.f,0.f,0.f,0.f}, sh = {0.f,0.f,0.f,0.f};
      if (shift) {
        sc = *(const f32x4*)(scale + spos * 256 + e);
        sh = *(const f32x4*)(shift + spos * 256 + e);
      }
      u16x4 o;
      #pragma unroll
      for (int i = 0; i < 4; ++i) {
        float ln = (v[j][i] - mean) * inv * gv[i] + bv[i];
        if (shift) ln = ln * (sc[i] + 1.0f) + sh[i];
        o[i] = f2b(ln);
      }
      *(u16x4*)(out + tb + e) = o;
    }
  } else {
    // lane owns elems 8l + 128j + i  (j=0..1, i=0..7)
    s16x8 r[2];
    #pragma unroll
    for (int j = 0; j < 2; ++j) r[j] = *(const s16x8*)(xb + tb + 8 * l + 128 * j);
    float v[2][8];
    float s = 0.f, s2 = 0.f;
    #pragma unroll
    for (int j = 0; j < 2; ++j)
      #pragma unroll
      for (int i = 0; i < 8; ++i) {
        const float f = b2f((u16)r[j][i]);
        v[j][i] = f; s += f; s2 += f * f;
      }
    #pragma unroll
    for (int off = 8; off >= 1; off >>= 1) {
      s  += __shfl_xor(s, off);
      s2 += __shfl_xor(s2, off);
    }
    const float mean = s * 0.00390625f;
    const float inv  = rsqrtf(s2 * 0.00390625f - mean * mean + 1e-5f);
    #pragma unroll
    for (int j = 0; j < 2; ++j) {
      const int e = 8 * l + 128 * j;
      const f32x4 g0 = *(const f32x4*)(g + e);
      const f32x4 g1 = *(const f32x4*)(g + e + 4);
      const f32x4 b0 = *(const f32x4*)(b + e);
      const f32x4 b1 = *(const f32x4*)(b + e + 4);
      s16x8 o;
      #pragma unroll
      for (int i = 0; i < 4; ++i) {
        o[i]     = (short)f2b((v[j][i]     - mean) * inv * g0[i] + b0[i]);
        o[i + 4] = (short)f2b((v[j][i + 4] - mean) * inv * g1[i] + b1[i]);
      }
      *(s16x8*)(out + tb + e) = o;
    }
  }
}

// ---------------------------------------------------------------------------
// Fused QKV GEMM: A(65536x256) bf16 @ {WqT,WkT,WvT}.
// grid (6, 512): x>>1 selects weight, x&1 selects n-half, y = m-block
// (x fastest -> 6 adjacent blocks share the A-tile -> L2/L3 reuse).
// q,k stored head-major [w][h][t][32]; v stored PV-frag-swizzled.
// ---------------------------------------------------------------------------
__global__ __launch_bounds__(256) void gemm_qkv(
    const u16* __restrict__ A, const u16* __restrict__ wt,
    const float* __restrict__ bq, const float* __restrict__ bk,
    const float* __restrict__ bv, u16* __restrict__ qo,
    u16* __restrict__ ko, u16* __restrict__ vo)
{
  __shared__ __align__(16) u16 Alds[128][72];
  __shared__ __align__(16) u16 Blds[128][72];
  const int wsel = blockIdx.x >> 1;
  const int m0 = blockIdx.y * 128;
  const int n0 = (blockIdx.x & 1) * 128;
  const u16* BT = wt + (size_t)wsel * 65536;
  const int t = threadIdx.x;
  const int wave = t >> 6, lane = t & 63;
  const int wm = (wave & 1) * 64, wn = (wave >> 1) * 64;
  const int lrow = lane & 15, lk = (lane >> 4) * 8;

  f32x4 acc[4][4];
  #pragma unroll
  for (int i = 0; i < 4; ++i)
    #pragma unroll
    for (int j = 0; j < 4; ++j)
      acc[i][j] = f32x4{0.f, 0.f, 0.f, 0.f};

  for (int k0 = 0; k0 < 256; k0 += 64) {
    #pragma unroll
    for (int i = 0; i < 4; ++i) {
      const int c = i * 256 + t;
      const int row = c >> 3, col = (c & 7) * 8;
      *(i32x4*)(&Alds[row][col]) = *(const i32x4*)(A  + (size_t)(m0 + row) * 256 + k0 + col);
      *(i32x4*)(&Blds[row][col]) = *(const i32x4*)(BT + (size_t)(n0 + row) * 256 + k0 + col);
    }
    __syncthreads();
    #pragma unroll
    for (int kk = 0; kk < 64; kk += 32) {
      s16x8 af[4], bf[4];
      #pragma unroll
      for (int mt = 0; mt < 4; ++mt) af[mt] = *(const s16x8*)(&Alds[wm + mt*16 + lrow][kk + lk]);
      #pragma unroll
      for (int nt = 0; nt < 4; ++nt) bf[nt] = *(const s16x8*)(&Blds[wn + nt*16 + lrow][kk + lk]);
      #pragma unroll
      for (int mt = 0; mt < 4; ++mt)
        #pragma unroll
        for (int nt = 0; nt < 4; ++nt)
          acc[mt][nt] = __builtin_amdgcn_mfma_f32_16x16x32_bf16(af[mt], bf[nt], acc[mt][nt], 0, 0, 0);
    }
    __syncthreads();
  }

  const float* bias = (wsel == 0) ? bq : (wsel == 1) ? bk : bv;
  u16* qko = (wsel == 0) ? qo : ko;
  #pragma unroll
  for (int mt = 0; mt < 4; ++mt) {
    const int mb = m0 + wm + mt*16 + (lane >> 4) * 4;
    const int w = mb >> 8, tok = mb & 255;
    #pragma unroll
    for (int nt = 0; nt < 4; ++nt) {
      const int n = n0 + wn + nt*16 + lrow;
      const int h = n >> 5, d = n & 31;
      const float bv_ = bias[n];
      if (wsel < 2) {
        #pragma unroll
        for (int r = 0; r < 4; ++r)
          qko[(size_t)w * 65536 + h * 8192 + (tok + r) * 32 + d] = f2b(acc[mt][nt][r] + bv_);
      } else {
        u16x4 pk;
        #pragma unroll
        for (int r = 0; r < 4; ++r) pk[r] = f2b(acc[mt][nt][r] + bv_);
        const int sgrp = tok >> 5, qp = (tok >> 3) & 3, j0 = tok & 7;
        *(u16x4*)(vo + (size_t)w * 65536 + h * 8192 + sgrp * 1024 + qp * 256 + d * 8 + j0) = pk;
      }
    }
  }
}

// ---------------------------------------------------------------------------
// GEMM: A(65536x256) bf16 @ WT[n][k] bf16. 128x128 tile, BK=64, 4 waves.
// grid (2, 512): x = n-half (fast dim -> A-tile L2 reuse), y = m-block.
// modes: 2 = bf16 out = extra_f + coef[n]*(acc+bias)        (Wo -> x1 bf16)
//        3 = bf16 out = silu(acc)                            (W1)
//        6 = fp32 out = b2f(extra_b) + coef[n]*acc           (W2 -> final x)
// ---------------------------------------------------------------------------
__global__ __launch_bounds__(256) void gemm256(
    const u16* __restrict__ A, const u16* __restrict__ BT,
    const float* __restrict__ bias, const float* __restrict__ extra_f,
    const u16* __restrict__ extra_b, const float* __restrict__ coef,
    u16* __restrict__ out_b, float* __restrict__ out_f, int mode)
{
  __shared__ __align__(16) u16 Alds[128][72];
  __shared__ __align__(16) u16 Blds[128][72];
  const int m0 = blockIdx.y * 128;
  const int n0 = blockIdx.x * 128;
  const int t = threadIdx.x;
  const int wave = t >> 6, lane = t & 63;
  const int wm = (wave & 1) * 64, wn = (wave >> 1) * 64;
  const int lrow = lane & 15, lk = (lane >> 4) * 8;

  f32x4 acc[4][4];
  #pragma unroll
  for (int i = 0; i < 4; ++i)
    #pragma unroll
    for (int j = 0; j < 4; ++j)
      acc[i][j] = f32x4{0.f, 0.f, 0.f, 0.f};

  for (int k0 = 0; k0 < 256; k0 += 64) {
    #pragma unroll
    for (int i = 0; i < 4; ++i) {
      const int c = i * 256 + t;
      const int row = c >> 3, col = (c & 7) * 8;
      *(i32x4*)(&Alds[row][col]) = *(const i32x4*)(A  + (size_t)(m0 + row) * 256 + k0 + col);
      *(i32x4*)(&Blds[row][col]) = *(const i32x4*)(BT + (size_t)(n0 + row) * 256 + k0 + col);
    }
    __syncthreads();
    #pragma unroll
    for (int kk = 0; kk < 64; kk += 32) {
      s16x8 af[4], bf[4];
      #pragma unroll
      for (int mt = 0; mt < 4; ++mt) af[mt] = *(const s16x8*)(&Alds[wm + mt*16 + lrow][kk + lk]);
      #pragma unroll
      for (int nt = 0; nt < 4; ++nt) bf[nt] = *(const s16x8*)(&Blds[wn + nt*16 + lrow][kk + lk]);
      #pragma unroll
      for (int mt = 0; mt < 4; ++mt)
        #pragma unroll
        for (int nt = 0; nt < 4; ++nt)
          acc[mt][nt] = __builtin_amdgcn_mfma_f32_16x16x32_bf16(af[mt], bf[nt], acc[mt][nt], 0, 0, 0);
    }
    __syncthreads();
  }

  #pragma unroll
  for (int mt = 0; mt < 4; ++mt) {
    const int mb = m0 + wm + mt*16 + (lane >> 4) * 4;
    #pragma unroll
    for (int nt = 0; nt < 4; ++nt) {
      const int n = n0 + wn + nt*16 + lrow;
      const float bv = bias ? bias[n] : 0.0f;
      #pragma unroll
      for (int r = 0; r < 4; ++r) {
        const int m = mb + r;
        const size_t oi = (size_t)m * 256 + n;
        const float y = acc[mt][nt][r] + bv;
        if (mode == 2)      out_b[oi] = f2b(extra_f[oi] + coef[n] * y);
        else if (mode == 3) out_b[oi] = f2b(y / (1.0f + __expf(-y)));
        else                out_f[oi] = b2f(extra_b[oi]) + coef[n] * y; // mode 6
      }
    }
  }
}

// ---------------------------------------------------------------------------
// Attention v3: grid (4, 8, 256) x 256 thr — q-tile fastest so the 4 blocks
// sharing a (w,h) K/V slice are dispatch-adjacent (L2/L3 reuse).
// Wave = 16 queries x 256 keys; register softmax (exp2 domain); single
// wave-private LDS transit for P; no barriers.
// ---------------------------------------------------------------------------
__global__ __launch_bounds__(256) void attn256(
    const u16* __restrict__ q, const u16* __restrict__ k,
    const u16* __restrict__ vt, const int* __restrict__ mask,
    u16* __restrict__ out)
{
  __shared__ __align__(16) u16 P[4][16][264];
  const int q0 = blockIdx.x * 64, h = blockIdx.y, w = blockIdx.z;
  const int t = threadIdx.x;
  const int wave = t >> 6, lane = t & 63;
  const int col = lane & 15, quad = lane >> 4;
  const size_t hb = (size_t)w * 65536 + (size_t)h * 8192;
  const int qr0 = q0 + wave * 16;
  const float sc2 = 0.25508586f;  // (1/sqrt(32)) * log2(e)

  float mbias[16];
  #pragma unroll
  for (int tl = 0; tl < 16; ++tl)
    mbias[tl] = (mask[w * 256 + tl * 16 + col] != 0) ? 0.0f : -1.0e9f;

  // ---- QK
  const s16x8 af = *(const s16x8*)(q + hb + (qr0 + col) * 32 + quad * 8);
  f32x4 acc[16];
  s16x8 kf[8];
  #pragma unroll
  for (int j = 0; j < 8; ++j)
    kf[j] = *(const s16x8*)(k + hb + (j * 16 + col) * 32 + quad * 8);
  #pragma unroll
  for (int j = 0; j < 8; ++j) {
    acc[j] = __builtin_amdgcn_mfma_f32_16x16x32_bf16(af, kf[j], f32x4{0.f,0.f,0.f,0.f}, 0, 0, 0);
    kf[j] = *(const s16x8*)(k + hb + ((8 + j) * 16 + col) * 32 + quad * 8);
  }
  #pragma unroll
  for (int j = 0; j < 8; ++j)
    acc[8 + j] = __builtin_amdgcn_mfma_f32_16x16x32_bf16(af, kf[j], f32x4{0.f,0.f,0.f,0.f}, 0, 0, 0);

  // ---- register softmax (exp2 domain)
  float inv[4];
  #pragma unroll
  for (int r = 0; r < 4; ++r) {
    float mx = -3.0e38f;
    #pragma unroll
    for (int tl = 0; tl < 16; ++tl) {
      const float p = fmaf(acc[tl][r], sc2, mbias[tl]);
      acc[tl][r] = p;
      mx = fmaxf(mx, p);
    }
    mx = fmaxf(mx, __shfl_xor(mx, 1));
    mx = fmaxf(mx, __shfl_xor(mx, 2));
    mx = fmaxf(mx, __shfl_xor(mx, 4));
    mx = fmaxf(mx, __shfl_xor(mx, 8));
    float sum = 0.f;
    #pragma unroll
    for (int tl = 0; tl < 16; ++tl) {
      const float e = exp2f(acc[tl][r] - mx);
      acc[tl][r] = e;
      sum += e;
    }
    sum += __shfl_xor(sum, 1);
    sum += __shfl_xor(sum, 2);
    sum += __shfl_xor(sum, 4);
    sum += __shfl_xor(sum, 8);
    inv[r] = 1.0f / sum;
  }

  // ---- P -> wave-private LDS (C-layout scatter)
  #pragma unroll
  for (int tl = 0; tl < 16; ++tl)
    #pragma unroll
    for (int r = 0; r < 4; ++r)
      P[wave][quad * 4 + r][tl * 16 + col] = f2b(acc[tl][r]);

  // ---- PV: O(16x32) = P(16x256) @ V(256x32), V pre-swizzled -> coalesced
  f32x4 o0 = {0.f,0.f,0.f,0.f}, o1 = {0.f,0.f,0.f,0.f};
  const u16* vb = vt + hb;
  #pragma unroll
  for (int s = 0; s < 8; ++s) {
    const s16x8 pf  = *(const s16x8*)(&P[wave][col][s * 32 + quad * 8]);
    const s16x8 vf0 = *(const s16x8*)(vb + s * 1024 + quad * 256 + col * 8);
    const s16x8 vf1 = *(const s16x8*)(vb + s * 1024 + quad * 256 + col * 8 + 128);
    o0 = __builtin_amdgcn_mfma_f32_16x16x32_bf16(pf, vf0, o0, 0, 0, 0);
    o1 = __builtin_amdgcn_mfma_f32_16x16x32_bf16(pf, vf1, o1, 0, 0, 0);
  }

  // ---- bounce O through the free P slab for 16B/lane stores
  #pragma unroll
  for (int r = 0; r < 4; ++r) {
    P[wave][quad * 4 + r][col]      = f2b(o0[r] * inv[r]);
    P[wave][quad * 4 + r][col + 16] = f2b(o1[r] * inv[r]);
  }
  const s16x8 ov = *(const s16x8*)(&P[wave][col][quad * 8]);
  *(s16x8*)(out + (size_t)w * 65536 + (size_t)(qr0 + col) * 256 + h * 32 + quad * 8) = ov;
}

// ---------------------------------------------------------------------------
// mask_update. grid 256 x 256.
// ---------------------------------------------------------------------------
__global__ __launch_bounds__(256) void maskup(const int* __restrict__ mask,
                                              float* __restrict__ out)
{
  __shared__ int wall[4];
  const int w = blockIdx.x, t = threadIdx.x;
  const int v = (mask[w * 256 + t] != 0) ? 1 : 0;
  const int a = __all(v);
  if ((t & 63) == 0) wall[t >> 6] = a;
  __syncthreads();
  const int allw = wall[0] & wall[1] & wall[2] & wall[3];
  out[w * 256 + t] = (v & allw) ? 1.0f : 0.0f;
}

// ---------------------------------------------------------------------------
extern "C" void kernel_launch(void* const* d_in, const int* in_sizes, int n_in,
                              void* d_out, int out_size, void* d_ws, size_t ws_size,
                              hipStream_t stream)
{
  (void)in_sizes; (void)n_in; (void)out_size; (void)ws_size;
  const float* x    = (const float*)d_in[0];
  const int*   mask = (const int*)d_in[1];
  const float* pos  = (const float*)d_in[2];
  const float* Wemb = (const float*)d_in[3];
  const float* bemb = (const float*)d_in[4];
  const float* ln1g = (const float*)d_in[5];
  const float* ln1b = (const float*)d_in[6];
  const float* Wq   = (const float*)d_in[7];
  const float* bq   = (const float*)d_in[8];
  const float* Wk   = (const float*)d_in[9];
  const float* bk   = (const float*)d_in[10];
  const float* Wv   = (const float*)d_in[11];
  const float* bv   = (const float*)d_in[12];
  const float* Wo   = (const float*)d_in[13];
  const float* bo   = (const float*)d_in[14];
  const float* ln2g = (const float*)d_in[15];
  const float* ln2b = (const float*)d_in[16];
  const float* W1   = (const float*)d_in[17];
  const float* W2   = (const float*)d_in[18];
  const float* gam  = (const float*)d_in[19];
  const float* gml  = (const float*)d_in[20];

  char* ws = (char*)d_ws;
  float* shift = (float*)ws;                       // 256 KB
  float* scale = (float*)(ws + (256 << 10));       // 256 KB
  u16*   wt    = (u16*)(ws + (512 << 10));         // 768 KB (6 x 256x256)
  u16*   b0    = (u16*)(ws + ((size_t)2  << 20));  // xm   -> attn_out
  u16*   b1    = (u16*)(ws + ((size_t)34 << 20));  // q^   -> x1 (bf16)
  u16*   b2    = (u16*)(ws + ((size_t)66 << 20));  // k^   -> ln2_out
  u16*   b3    = (u16*)(ws + ((size_t)98 << 20));  // V~   -> silu(h1)
  float* outx  = (float*)d_out;
  float* outm  = outx + 16777216;

  const u16* WoT = wt + 3 * 65536;
  const u16* W1T = wt + 4 * 65536;
  const u16* W2T = wt + 5 * 65536;

  transpose6<<<dim3(6, 16), 256, 0, stream>>>(Wq, Wk, Wv, Wo, W1, W2, wt);
  film_kernel<<<dim3(256, 8), 256, 0, stream>>>(pos, Wemb, bemb, shift, scale);
  ln_kernel<<<4096, 256, 0, stream>>>(x, nullptr, shift, scale, ln1g, ln1b, b0);
  gemm_qkv<<<dim3(6, 512), 256, 0, stream>>>(b0, wt, bq, bk, bv, b1, b2, b3);
  attn256<<<dim3(4, 8, 256), 256, 0, stream>>>(b1, b2, b3, mask, b0);
  // x1 = bf16(x + gamma * (attn_out @ Wo + bo))
  gemm256<<<dim3(2, 512), 256, 0, stream>>>(b0, WoT, bo, x, nullptr, gam, b1, nullptr, 2);
  ln_kernel<<<4096, 256, 0, stream>>>(nullptr, b1, nullptr, nullptr, ln2g, ln2b, b2);
  gemm256<<<dim3(2, 512), 256, 0, stream>>>(b2, W1T, nullptr, nullptr, nullptr, nullptr, b3, nullptr, 3);
  // out = x1 + gamma_mlp * (h @ W2)   (fp32 final)
  gemm256<<<dim3(2, 512), 256, 0, stream>>>(b3, W2T, nullptr, nullptr, b1, gml, nullptr, outx, 6);
  maskup<<<256, 256, 0, stream>>>(mask, outm);
}